// Round 7
// baseline (992.326 us; speedup 1.0000x reference)
//
#include <hip/hip_runtime.h>
#include <stdint.h>

#define N_PTS 4096
#define S_PTS 1024
#define K_SAMP 32
#define NWORK 248          // consumer blocks; 8 + NWORK = 256 = 1 block/CU (LDS-forced)
#define RSTRIDE 16         // ints per ready-slot (64 B) — each word polled by ONE block

typedef __attribute__((ext_vector_type(8))) short bf16x8;
typedef __attribute__((ext_vector_type(4))) float f32x4;

#define GT1_S 104   // 96 cols + 8 pad (keeps b128 reads at <=2-way bank aliasing)
#define GT2_S 72    // 64 + 8
#define GT3_S 136   // 128 + 8

__device__ __forceinline__ short f2b(float f){
  unsigned u = __float_as_uint(f);
  u = u + 0x7fffu + ((u >> 16) & 1u);   // RNE to bf16
  return (short)(u >> 16);
}

// DPP ctrl encodings (gfx9 lineage)
#define DPP_QUAD_XOR1 0xB1   // quad_perm(1,0,3,2)
#define DPP_QUAD_XOR2 0x4E   // quad_perm(2,3,0,1)
#define DPP_ROW_HMIRR 0x141  // row_half_mirror
#define DPP_ROW_MIRR  0x140  // row_mirror
#define DPP_ROW_BC15  0x142  // row_bcast15
#define DPP_ROW_BC31  0x143  // row_bcast31

// one butterfly/bcast stage of u64-key max (key = dist_bits<<32 | ~idx;
// max => largest dist, tie -> smallest idx). max is idempotent, so the
// bcast stages' partial-overlap duplicates are harmless.
template<int CTRL>
__device__ __forceinline__ unsigned long long kstep(unsigned long long k){
  unsigned lo = (unsigned)k, hi = (unsigned)(k >> 32);
  unsigned lo2 = (unsigned)__builtin_amdgcn_update_dpp((int)lo, (int)lo, CTRL, 0xF, 0xF, false);
  unsigned hi2 = (unsigned)__builtin_amdgcn_update_dpp((int)hi, (int)hi, CTRL, 0xF, 0xF, false);
  unsigned long long ok = ((unsigned long long)hi2 << 32) | lo2;
  return ok > k ? ok : k;
}

// ---------------------------------------------------------------------------
// Weights -> bf16 in ws; also zeroes the ready array (stream-ordered before
// the fused kernel, so graph replays never observe stale flags).
// ---------------------------------------------------------------------------
__global__ void wconv_kernel(const float* __restrict__ W1,
                             const float* __restrict__ W2,
                             const float* __restrict__ W3,
                             short* __restrict__ ws_w,
                             int* __restrict__ ready){
  short* w1 = ws_w;                       // 64 x 96
  short* w2 = ws_w + 64*96;               // 128 x 64
  short* w3 = ws_w + 64*96 + 128*64;      // 256 x 128
  int t = blockIdx.x * blockDim.x + threadIdx.x;
  int stride = gridDim.x * blockDim.x;
  for (int i = t; i < 8*S_PTS*RSTRIDE; i += stride) ready[i] = 0;
  for (int i = t; i < 64*96; i += stride){
    int m = i / 96, k = i - m*96;
    float v = 0.0f;
    if (k < 64)      v = W1[m*67 + 3 + k];
    else if (k < 67) v = W1[m*67 + (k - 64)];
    w1[i] = f2b(v);
  }
  for (int i = t; i < 128*64;  i += stride) w2[i] = f2b(W2[i]);
  for (int i = t; i < 256*128; i += stride) w3[i] = f2b(W3[i]);
}

// ---------------------------------------------------------------------------
// MFMA layer helper (unchanged)
// ---------------------------------------------------------------------------
template<int M, int KC, int KPAD, int GS_IN, int GS_OUT>
__device__ __forceinline__ void layer_mfma(const short* __restrict__ Wl,
                                           const short* gin, short* gout,
                                           const float* __restrict__ sbias_l,
                                           int w, int quad, int col){
  for (int m0 = w*16; m0 < M; m0 += 64){
    f32x4 acc0 = {0,0,0,0}, acc1 = {0,0,0,0};
#pragma unroll
    for (int kc = 0; kc < KC; ++kc){
      bf16x8 a  = *reinterpret_cast<const bf16x8*>(Wl + (size_t)(m0+col)*KPAD + kc*32 + quad*8);
      bf16x8 b0 = *reinterpret_cast<const bf16x8*>(gin + col*GS_IN + kc*32 + quad*8);
      bf16x8 b1 = *reinterpret_cast<const bf16x8*>(gin + (16+col)*GS_IN + kc*32 + quad*8);
      acc0 = __builtin_amdgcn_mfma_f32_16x16x32_bf16(a, b0, acc0, 0, 0, 0);
      acc1 = __builtin_amdgcn_mfma_f32_16x16x32_bf16(a, b1, acc1, 0, 0, 0);
    }
    int rbase = m0 + quad*4;
    unsigned long long P0 = 0ull, P1 = 0ull;
#pragma unroll
    for (int r = 0; r < 4; ++r){
      float bias = sbias_l[rbase + r];
      unsigned long long q0 = (unsigned short)f2b(fmaxf(acc0[r] + bias, 0.0f));
      unsigned long long q1 = (unsigned short)f2b(fmaxf(acc1[r] + bias, 0.0f));
      P0 |= q0 << (16*r);
      P1 |= q1 << (16*r);
    }
    *reinterpret_cast<unsigned long long*>(&gout[col*GS_OUT + rbase])      = P0;
    *reinterpret_cast<unsigned long long*>(&gout[(16+col)*GS_OUT + rbase]) = P1;
  }
}

// ---------------------------------------------------------------------------
// Fused producer/consumer kernel, v4:
//   - LDS padded to 82,400 B  =>  1 block/CU (2x82400 > 160KiB). Producers run
//     ALONE on their 8 CUs — identical conditions to the 604us standalone fps.
//     (Round-6 falsifier: setprio was null => interference was block-level
//     LDS/barrier contention, not issue arbitration. So evict, don't outrank.)
//   - grid = 8 + 248 = 256 blocks = 256 CUs, all co-resident by construction:
//     deadlock-free regardless of dispatch order.
//   - producer publishes ONE relaxed u32 (idx+1) per center to a 64B-strided
//     ready word: no waitcnt, no release, no shared hot line.
//   - consumer re-derives center coords from the read-only xyz input
//     (bit-identical to the producer's), so no acquire is needed.
//   - consumers write out_feat DIRECTLY in (b,c,s) layout (scattered 4B
//     stores, hidden under the producer-limited timeline).
// Exact numpy f32 semantics preserved (per-op RNE, no FMA, (x+y)+z order,
// fminf, argmax tie -> lowest index).
// ---------------------------------------------------------------------------
__global__ __launch_bounds__(256) void fused_kernel(
    const float* __restrict__ xyz, const float* __restrict__ feat,
    const float* __restrict__ b1, const float* __restrict__ b2,
    const float* __restrict__ b3, const short* __restrict__ ws_w,
    float* __restrict__ out_newxyz, float* __restrict__ out_inds,
    int* __restrict__ ready, float* __restrict__ out_feat){

  __shared__ __align__(16) union ShU {
    struct { float4 c4[N_PTS]; unsigned long long slots[2][4]; } f;   // 65600 B
    struct { short gT1[32*GT1_S]; short gT2[32*GT2_S]; short gT3[32*GT3_S];
             int sidx[K_SAMP]; float sbias[448]; int cidx; } m;       // 21896 B
    char pad[82400];   // force 1 block/CU: 2*82400 > 163840
  } sh;

  const int t = threadIdx.x;
  const int lane = t & 63;
  const int w = t >> 6;

  if (blockIdx.x < 8){
    // ------------------------- FPS producer -------------------------
    const int b = blockIdx.x;
    const float* xb = xyz + (size_t)b * N_PTS * 3;

    float px[16], py[16], pz[16], dist[16];
#pragma unroll
    for (int j = 0; j < 16; ++j){
      int p = j * 256 + t;
      float x = xb[p*3+0], y = xb[p*3+1], z = xb[p*3+2];
      px[j] = x; py[j] = y; pz[j] = z; dist[j] = 1e10f;
      sh.f.c4[p] = make_float4(x, y, z, 0.0f);
    }
    __syncthreads();

    float lx, ly, lz;
    { float4 c0 = sh.f.c4[0]; lx = c0.x; ly = c0.y; lz = c0.z; }
    if (t == 0){
      out_inds[(size_t)b * S_PTS] = 0.0f;
      out_newxyz[(size_t)b*S_PTS*3 + 0] = lx;
      out_newxyz[(size_t)b*S_PTS*3 + 1] = ly;
      out_newxyz[(size_t)b*S_PTS*3 + 2] = lz;
      __hip_atomic_store(&ready[(size_t)b*S_PTS*RSTRIDE], 1,
                         __ATOMIC_RELAXED, __HIP_MEMORY_SCOPE_AGENT);
    }

    for (int it = 1; it < S_PTS; ++it){
      // --- local distance update + fused argmax (straight-line, registers) ---
      float bv = -1.0f; int bj = 0;
#pragma unroll
      for (int j = 0; j < 16; ++j){
        float dx = __fsub_rn(px[j], lx);
        float dy = __fsub_rn(py[j], ly);
        float dz = __fsub_rn(pz[j], lz);
        float d  = __fadd_rn(__fadd_rn(__fmul_rn(dx,dx), __fmul_rn(dy,dy)), __fmul_rn(dz,dz));
        float nd = fminf(dist[j], d);
        dist[j] = nd;
        bool gt = nd > bv;               // strict >, j ascending => lowest j kept
        bv = gt ? nd : bv;
        bj = gt ? j  : bj;
      }
      int bi = bj * 256 + t;             // global point index
      unsigned long long k = ((unsigned long long)__float_as_uint(bv) << 32)
                           | (unsigned)(~bi);

      // --- wave64 argmax butterfly via DPP (all VALU-rate, no LDS) ---
      k = kstep<DPP_QUAD_XOR1>(k);
      k = kstep<DPP_QUAD_XOR2>(k);
      k = kstep<DPP_ROW_HMIRR>(k);
      k = kstep<DPP_ROW_MIRR >(k);
      k = kstep<DPP_ROW_BC15 >(k);
      k = kstep<DPP_ROW_BC31 >(k);       // lanes 48..63 hold the wave total

      if (lane == 63) sh.f.slots[it & 1][w] = k;
      __syncthreads();                   // the only barrier per iteration

      unsigned long long sk = sh.f.slots[it & 1][lane & 3];
      sk = kstep<DPP_QUAD_XOR1>(sk);
      sk = kstep<DPP_QUAD_XOR2>(sk);
      int cur = (int)(~(unsigned)sk);

      float4 cc = sh.f.c4[cur];          // same-address broadcast, conflict-free
      lx = cc.x; ly = cc.y; lz = cc.z;
      if (t == 0){
        out_inds[(size_t)b*S_PTS + it] = (float)cur;
        out_newxyz[((size_t)b*S_PTS + it)*3 + 0] = lx;
        out_newxyz[((size_t)b*S_PTS + it)*3 + 1] = ly;
        out_newxyz[((size_t)b*S_PTS + it)*3 + 2] = lz;
        // fire-and-forget publish: relaxed => no waitcnt, off critical path
        __hip_atomic_store(&ready[((size_t)b*S_PTS + it)*RSTRIDE], cur + 1,
                           __ATOMIC_RELAXED, __HIP_MEMORY_SCOPE_AGENT);
      }
    }
    return;
  }

  // ------------------------- consumer: ball query + MLP -------------------------
  const int wid = blockIdx.x - 8;
  const int quad = lane >> 4;
  const int col = lane & 15;
  const short* w1 = ws_w;
  const short* w2 = ws_w + 64*96;
  const short* w3 = ws_w + 64*96 + 128*64;

  for (int i = t; i < 448; i += 256)
    sh.m.sbias[i] = (i < 64) ? b1[i] : (i < 192) ? b2[i-64] : b3[i-192];
  for (int i = t; i < 32*GT1_S; i += 256) sh.m.gT1[i] = 0;   // pad cols stay 0

  for (int c = wid; c < 8*S_PTS; c += NWORK){
    const int b = c >> 10;
    const int s = c & (S_PTS - 1);

    if (t == 0){
      int v;
      while ((v = __hip_atomic_load(&ready[(size_t)c*RSTRIDE],
                                    __ATOMIC_RELAXED, __HIP_MEMORY_SCOPE_AGENT)) == 0)
        __builtin_amdgcn_s_sleep(4);
      sh.m.cidx = v - 1;
    }
    __syncthreads();                     // also orders prev center's LDS reuse
    const int cen = sh.m.cidx;
    const float* pc = xyz + ((size_t)b * N_PTS + cen) * 3;
    const float cx = pc[0], cy = pc[1], cz = pc[2];   // same bits the producer stored

    // --- ball query (wave 0 only), ordered first-32 selection via ballot ---
    if (w == 0){
      const float* xb = xyz + (size_t)b * N_PTS * 3;
      const float R2 = 0.2f * 0.2f;
      int have = 0, first = -1;
      for (int chunk = 0; chunk < 64 && have < K_SAMP; ++chunk){
        int p = chunk * 64 + lane;
        float dx = __fsub_rn(xb[p*3+0], cx);
        float dy = __fsub_rn(xb[p*3+1], cy);
        float dz = __fsub_rn(xb[p*3+2], cz);
        float d2 = __fadd_rn(__fadd_rn(__fmul_rn(dx,dx), __fmul_rn(dy,dy)), __fmul_rn(dz,dz));
        bool hit = d2 < R2;
        unsigned long long mask = __ballot(hit);
        if (mask){
          if (first < 0) first = chunk*64 + (__ffsll(mask) - 1);
          int pre = __popcll(mask & ((1ull << lane) - 1ull));
          if (hit && (have + pre) < K_SAMP) sh.m.sidx[have + pre] = p;
          have += __popcll(mask);
          if (have > K_SAMP) have = K_SAMP;
        }
      }
      if (first < 0) first = 0;
      if (lane < K_SAMP - have) sh.m.sidx[have + lane] = first;
    }
    __syncthreads();

    // --- gather: features -> gT1[p][0..63], relative xyz -> gT1[p][64..66] ---
    {
      int p = t >> 3, q = t & 7;
      int src = sh.m.sidx[p];
      const float* fr = feat + ((size_t)b * N_PTS + src) * 64 + q*8;
      unsigned u[4];
#pragma unroll
      for (int jj = 0; jj < 4; ++jj){
        unsigned lo = (unsigned short)f2b(fr[2*jj]);
        unsigned hi = (unsigned short)f2b(fr[2*jj+1]);
        u[jj] = lo | (hi << 16);
      }
      uint4 v; v.x = u[0]; v.y = u[1]; v.z = u[2]; v.w = u[3];
      *reinterpret_cast<uint4*>(&sh.m.gT1[p*GT1_S + q*8]) = v;
    }
    if (t < 32){
      int src = sh.m.sidx[t];
      const float* pr = xyz + ((size_t)b * N_PTS + src) * 3;
      sh.m.gT1[t*GT1_S + 64] = f2b(__fsub_rn(pr[0], cx));
      sh.m.gT1[t*GT1_S + 65] = f2b(__fsub_rn(pr[1], cy));
      sh.m.gT1[t*GT1_S + 66] = f2b(__fsub_rn(pr[2], cz));
    }
    __syncthreads();

    layer_mfma<64, 3, 96, GT1_S, GT2_S>(w1, sh.m.gT1, sh.m.gT2, sh.m.sbias, w, quad, col);
    __syncthreads();
    layer_mfma<128, 2, 64, GT2_S, GT3_S>(w2, sh.m.gT2, sh.m.gT3, sh.m.sbias + 64, w, quad, col);
    __syncthreads();

    // --- layer 3 + max-pool + DIRECT transposed store to out_feat(b,c,s) ---
    for (int m0 = w*16; m0 < 256; m0 += 64){
      f32x4 acc0 = {0,0,0,0}, acc1 = {0,0,0,0};
#pragma unroll
      for (int kc = 0; kc < 4; ++kc){
        bf16x8 a  = *reinterpret_cast<const bf16x8*>(w3 + (size_t)(m0+col)*128 + kc*32 + quad*8);
        bf16x8 b0 = *reinterpret_cast<const bf16x8*>(sh.m.gT3 + col*GT3_S + kc*32 + quad*8);
        bf16x8 b1 = *reinterpret_cast<const bf16x8*>(sh.m.gT3 + (16+col)*GT3_S + kc*32 + quad*8);
        acc0 = __builtin_amdgcn_mfma_f32_16x16x32_bf16(a, b0, acc0, 0, 0, 0);
        acc1 = __builtin_amdgcn_mfma_f32_16x16x32_bf16(a, b1, acc1, 0, 0, 0);
      }
      float vm[4];
#pragma unroll
      for (int r = 0; r < 4; ++r) vm[r] = fmaxf(acc0[r], acc1[r]);
#pragma unroll
      for (int off = 1; off < 16; off <<= 1){
#pragma unroll
        for (int r = 0; r < 4; ++r) vm[r] = fmaxf(vm[r], __shfl_xor(vm[r], off, 16));
      }
      if (col == 0){
#pragma unroll
        for (int r = 0; r < 4; ++r){
          int ch = m0 + quad*4 + r;
          out_feat[((size_t)b*256 + ch)*S_PTS + s] =
              fmaxf(vm[r] + sh.m.sbias[192 + ch], 0.0f);
        }
      }
    }
    // no tail barrier: next iteration's poll-__syncthreads protects LDS reuse
  }
}

extern "C" void kernel_launch(void* const* d_in, const int* in_sizes, int n_in,
                              void* d_out, int out_size, void* d_ws, size_t ws_size,
                              hipStream_t stream){
  const float* xyz  = (const float*)d_in[0];
  const float* feat = (const float*)d_in[1];
  const float* W1   = (const float*)d_in[2];
  const float* b1   = (const float*)d_in[3];
  const float* W2   = (const float*)d_in[4];
  const float* b2   = (const float*)d_in[5];
  const float* W3   = (const float*)d_in[6];
  const float* b3   = (const float*)d_in[7];

  float* out        = (float*)d_out;
  float* out_newxyz = out;                        // 8*1024*3   = 24576
  float* out_feat   = out + 24576;                // 8*256*1024 = 2097152
  float* out_inds   = out + 24576 + 2097152;      // 8*1024     = 8192 (as float)

  char*  ws     = (char*)d_ws;
  short* ws_w   = (short*)ws;                       // 94208 B of bf16 weights
  int*   ready  = (int*)(ws + 94208);               // 8192 x 64B ready slots = 512 KB

  wconv_kernel<<<32, 256, 0, stream>>>(W1, W2, W3, ws_w, ready);
  fused_kernel<<<8 + NWORK, 256, 0, stream>>>(xyz, feat, b1, b2, b3, ws_w,
                                              out_newxyz, out_inds, ready, out_feat);
}

// Round 8
// 798.619 us; speedup vs baseline: 1.2426x; 1.2426x over previous
//
#include <hip/hip_runtime.h>
#include <stdint.h>

#define N_PTS 4096
#define S_PTS 1024
#define K_SAMP 32
#define NCONS 504          // consumer blocks; 8 + NCONS = 512 = 2 blocks/CU, all co-resident
#define RSTRIDE 16         // ints per ready-slot (64 B)

typedef __attribute__((ext_vector_type(8))) short bf16x8;
typedef __attribute__((ext_vector_type(4))) float f32x4;

#define GT1_S 104   // 96 cols + 8 pad (keeps b128 reads at <=2-way bank aliasing)
#define GT2_S 72    // 64 + 8
#define GT3_S 136   // 128 + 8

__device__ __forceinline__ short f2b(float f){
  unsigned u = __float_as_uint(f);
  u = u + 0x7fffu + ((u >> 16) & 1u);   // RNE to bf16
  return (short)(u >> 16);
}

// physical CU identity: HW_ID bits[15:8] = CU_ID|SH_ID|SE_ID, plus XCC_ID.
// Used only as an opaque CU tag (collisions merely evict a spare consumer).
__device__ __forceinline__ int cu_tag(){
  unsigned hwid, xcc;
  asm volatile("s_getreg_b32 %0, hwreg(HW_REG_HW_ID)" : "=s"(hwid));
  asm volatile("s_getreg_b32 %0, hwreg(HW_REG_XCC_ID)" : "=s"(xcc));
  return (int)(((hwid >> 8) & 0xFFu) | (xcc << 8)) + 1;   // +1 so 0 == "unset"
}

// DPP ctrl encodings (gfx9 lineage)
#define DPP_QUAD_XOR1 0xB1   // quad_perm(1,0,3,2)
#define DPP_QUAD_XOR2 0x4E   // quad_perm(2,3,0,1)
#define DPP_ROW_HMIRR 0x141  // row_half_mirror
#define DPP_ROW_MIRR  0x140  // row_mirror
#define DPP_ROW_BC15  0x142  // row_bcast15
#define DPP_ROW_BC31  0x143  // row_bcast31

// one butterfly/bcast stage of u64-key max (key = dist_bits<<32 | ~idx;
// max => largest dist, tie -> smallest idx). max is idempotent, so the
// bcast stages' partial-overlap duplicates are harmless.
template<int CTRL>
__device__ __forceinline__ unsigned long long kstep(unsigned long long k){
  unsigned lo = (unsigned)k, hi = (unsigned)(k >> 32);
  unsigned lo2 = (unsigned)__builtin_amdgcn_update_dpp((int)lo, (int)lo, CTRL, 0xF, 0xF, false);
  unsigned hi2 = (unsigned)__builtin_amdgcn_update_dpp((int)hi, (int)hi, CTRL, 0xF, 0xF, false);
  unsigned long long ok = ((unsigned long long)hi2 << 32) | lo2;
  return ok > k ? ok : k;
}

// ---------------------------------------------------------------------------
// Weights -> bf16 in ws; zeroes ready[] and ctrl[] (stream-ordered before the
// fused kernel, so graph replays never observe stale flags).
// ---------------------------------------------------------------------------
__global__ void wconv_kernel(const float* __restrict__ W1,
                             const float* __restrict__ W2,
                             const float* __restrict__ W3,
                             short* __restrict__ ws_w,
                             int* __restrict__ ready,
                             int* __restrict__ ctrl){
  short* w1 = ws_w;                       // 64 x 96
  short* w2 = ws_w + 64*96;               // 128 x 64
  short* w3 = ws_w + 64*96 + 128*64;      // 256 x 128
  int t = blockIdx.x * blockDim.x + threadIdx.x;
  int stride = gridDim.x * blockDim.x;
  if (t < 16) ctrl[t] = 0;                // [0..7] producer CU tags, [8] queue
  for (int i = t; i < 8*S_PTS*RSTRIDE; i += stride) ready[i] = 0;
  for (int i = t; i < 64*96; i += stride){
    int m = i / 96, k = i - m*96;
    float v = 0.0f;
    if (k < 64)      v = W1[m*67 + 3 + k];
    else if (k < 67) v = W1[m*67 + (k - 64)];
    w1[i] = f2b(v);
  }
  for (int i = t; i < 128*64;  i += stride) w2[i] = f2b(W2[i]);
  for (int i = t; i < 256*128; i += stride) w3[i] = f2b(W3[i]);
}

// ---------------------------------------------------------------------------
// MFMA layer helper (unchanged)
// ---------------------------------------------------------------------------
template<int M, int KC, int KPAD, int GS_IN, int GS_OUT>
__device__ __forceinline__ void layer_mfma(const short* __restrict__ Wl,
                                           const short* gin, short* gout,
                                           const float* __restrict__ sbias_l,
                                           int w, int quad, int col){
  for (int m0 = w*16; m0 < M; m0 += 64){
    f32x4 acc0 = {0,0,0,0}, acc1 = {0,0,0,0};
#pragma unroll
    for (int kc = 0; kc < KC; ++kc){
      bf16x8 a  = *reinterpret_cast<const bf16x8*>(Wl + (size_t)(m0+col)*KPAD + kc*32 + quad*8);
      bf16x8 b0 = *reinterpret_cast<const bf16x8*>(gin + col*GS_IN + kc*32 + quad*8);
      bf16x8 b1 = *reinterpret_cast<const bf16x8*>(gin + (16+col)*GS_IN + kc*32 + quad*8);
      acc0 = __builtin_amdgcn_mfma_f32_16x16x32_bf16(a, b0, acc0, 0, 0, 0);
      acc1 = __builtin_amdgcn_mfma_f32_16x16x32_bf16(a, b1, acc1, 0, 0, 0);
    }
    int rbase = m0 + quad*4;
    unsigned long long P0 = 0ull, P1 = 0ull;
#pragma unroll
    for (int r = 0; r < 4; ++r){
      float bias = sbias_l[rbase + r];
      unsigned long long q0 = (unsigned short)f2b(fmaxf(acc0[r] + bias, 0.0f));
      unsigned long long q1 = (unsigned short)f2b(fmaxf(acc1[r] + bias, 0.0f));
      P0 |= q0 << (16*r);
      P1 |= q1 << (16*r);
    }
    *reinterpret_cast<unsigned long long*>(&gout[col*GS_OUT + rbase])      = P0;
    *reinterpret_cast<unsigned long long*>(&gout[(16+col)*GS_OUT + rbase]) = P1;
  }
}

// ---------------------------------------------------------------------------
// Fused producer/consumer kernel, v5:
//   - 2 blocks/CU (65.6 KB LDS union, 512 blocks) — the VGPR-88 codegen and
//     8-wave consumer CUs of r5/r6, which measured best for both roles.
//   - NEW: producer-CU eviction. Each producer publishes its physical CU tag
//     (s_getreg HW_ID + XCC_ID) to ctrl[b]; consumers wait for all 8 tags
//     (producers are co-resident by construction => they all start), then any
//     consumer sharing a CU with a producer EXITS. Producer CUs run the
//     producer ALONE = the measured-604us standalone condition. r6 showed
//     setprio can't fix this contention (LDS pipe + barrier slots, not issue
//     arbitration) — eviction removes it physically.
//   - NEW: atomic work queue (ctrl[8]) replaces static center assignment, so
//     evicted blocks' work redistributes automatically.
//   - producer publish: ONE relaxed u32 (idx+1) per center, 64B-strided.
//   - consumer re-derives center coords from read-only xyz (bit-identical),
//     so no acquire is needed anywhere.
//   - consumers write out_feat directly in (b,c,s) layout (r6: timing-neutral,
//     deletes the transpose dispatch + 16MB round-trip).
// Exact numpy f32 semantics preserved (per-op RNE, no FMA, (x+y)+z order,
// fminf, argmax tie -> lowest index).
// ---------------------------------------------------------------------------
__global__ __launch_bounds__(256) void fused_kernel(
    const float* __restrict__ xyz, const float* __restrict__ feat,
    const float* __restrict__ b1, const float* __restrict__ b2,
    const float* __restrict__ b3, const short* __restrict__ ws_w,
    float* __restrict__ out_newxyz, float* __restrict__ out_inds,
    int* __restrict__ ready, int* __restrict__ ctrl,
    float* __restrict__ out_feat){

  __shared__ __align__(16) union ShU {
    struct { float4 c4[N_PTS]; unsigned long long slots[2][4]; } f;   // 65600 B
    struct { short gT1[32*GT1_S]; short gT2[32*GT2_S]; short gT3[32*GT3_S];
             int sidx[K_SAMP]; float sbias[448]; int cidx; int qc; } m;
  } sh;

  const int t = threadIdx.x;
  const int lane = t & 63;
  const int w = t >> 6;

  if (blockIdx.x < 8){
    // ------------------------- FPS producer -------------------------
    const int b = blockIdx.x;
    if (t == 0)
      __hip_atomic_store(&ctrl[b], cu_tag(),
                         __ATOMIC_RELAXED, __HIP_MEMORY_SCOPE_AGENT);
    const float* xb = xyz + (size_t)b * N_PTS * 3;

    float px[16], py[16], pz[16], dist[16];
#pragma unroll
    for (int j = 0; j < 16; ++j){
      int p = j * 256 + t;
      float x = xb[p*3+0], y = xb[p*3+1], z = xb[p*3+2];
      px[j] = x; py[j] = y; pz[j] = z; dist[j] = 1e10f;
      sh.f.c4[p] = make_float4(x, y, z, 0.0f);
    }
    __syncthreads();

    float lx, ly, lz;
    { float4 c0 = sh.f.c4[0]; lx = c0.x; ly = c0.y; lz = c0.z; }
    if (t == 0){
      out_inds[(size_t)b * S_PTS] = 0.0f;
      out_newxyz[(size_t)b*S_PTS*3 + 0] = lx;
      out_newxyz[(size_t)b*S_PTS*3 + 1] = ly;
      out_newxyz[(size_t)b*S_PTS*3 + 2] = lz;
      __hip_atomic_store(&ready[(size_t)b*S_PTS*RSTRIDE], 1,
                         __ATOMIC_RELAXED, __HIP_MEMORY_SCOPE_AGENT);
    }

    for (int it = 1; it < S_PTS; ++it){
      // --- local distance update + fused argmax (straight-line, registers) ---
      float bv = -1.0f; int bj = 0;
#pragma unroll
      for (int j = 0; j < 16; ++j){
        float dx = __fsub_rn(px[j], lx);
        float dy = __fsub_rn(py[j], ly);
        float dz = __fsub_rn(pz[j], lz);
        float d  = __fadd_rn(__fadd_rn(__fmul_rn(dx,dx), __fmul_rn(dy,dy)), __fmul_rn(dz,dz));
        float nd = fminf(dist[j], d);
        dist[j] = nd;
        bool gt = nd > bv;               // strict >, j ascending => lowest j kept
        bv = gt ? nd : bv;
        bj = gt ? j  : bj;
      }
      int bi = bj * 256 + t;             // global point index
      unsigned long long k = ((unsigned long long)__float_as_uint(bv) << 32)
                           | (unsigned)(~bi);

      // --- wave64 argmax butterfly via DPP (all VALU-rate, no LDS) ---
      k = kstep<DPP_QUAD_XOR1>(k);
      k = kstep<DPP_QUAD_XOR2>(k);
      k = kstep<DPP_ROW_HMIRR>(k);
      k = kstep<DPP_ROW_MIRR >(k);
      k = kstep<DPP_ROW_BC15 >(k);
      k = kstep<DPP_ROW_BC31 >(k);       // lanes 48..63 hold the wave total

      if (lane == 63) sh.f.slots[it & 1][w] = k;
      __syncthreads();                   // the only barrier per iteration

      unsigned long long sk = sh.f.slots[it & 1][lane & 3];
      sk = kstep<DPP_QUAD_XOR1>(sk);
      sk = kstep<DPP_QUAD_XOR2>(sk);
      int cur = (int)(~(unsigned)sk);

      float4 cc = sh.f.c4[cur];          // same-address broadcast, conflict-free
      lx = cc.x; ly = cc.y; lz = cc.z;
      if (t == 0){
        out_inds[(size_t)b*S_PTS + it] = (float)cur;
        out_newxyz[((size_t)b*S_PTS + it)*3 + 0] = lx;
        out_newxyz[((size_t)b*S_PTS + it)*3 + 1] = ly;
        out_newxyz[((size_t)b*S_PTS + it)*3 + 2] = lz;
        // fire-and-forget publish: relaxed => no waitcnt, off critical path
        __hip_atomic_store(&ready[((size_t)b*S_PTS + it)*RSTRIDE], cur + 1,
                           __ATOMIC_RELAXED, __HIP_MEMORY_SCOPE_AGENT);
      }
    }
    return;
  }

  // ------------------------- consumer: ball query + MLP -------------------------
  // Eviction check: wait for all 8 producer CU tags, exit if we share a CU.
  if (t == 0){
    for (int i = 0; i < 8; ++i)
      while (__hip_atomic_load(&ctrl[i], __ATOMIC_RELAXED, __HIP_MEMORY_SCOPE_AGENT) == 0)
        __builtin_amdgcn_s_sleep(8);
    int my = cu_tag(), on = 0;
    for (int i = 0; i < 8; ++i)
      on |= (__hip_atomic_load(&ctrl[i], __ATOMIC_RELAXED, __HIP_MEMORY_SCOPE_AGENT) == my);
    sh.m.qc = on;
  }
  __syncthreads();
  if (sh.m.qc) return;                   // vacate the producer's CU

  const int quad = lane >> 4;
  const int col = lane & 15;
  const short* w1 = ws_w;
  const short* w2 = ws_w + 64*96;
  const short* w3 = ws_w + 64*96 + 128*64;

  for (int i = t; i < 448; i += 256)
    sh.m.sbias[i] = (i < 64) ? b1[i] : (i < 192) ? b2[i-64] : b3[i-192];
  for (int i = t; i < 32*GT1_S; i += 256) sh.m.gT1[i] = 0;   // pad cols stay 0

  for (;;){
    if (t == 0){
      int c = __hip_atomic_fetch_add(&ctrl[8], 1,
                                     __ATOMIC_RELAXED, __HIP_MEMORY_SCOPE_AGENT);
      sh.m.qc = c;
      if (c < 8*S_PTS){
        int v;
        while ((v = __hip_atomic_load(&ready[(size_t)c*RSTRIDE],
                                      __ATOMIC_RELAXED, __HIP_MEMORY_SCOPE_AGENT)) == 0)
          __builtin_amdgcn_s_sleep(4);
        sh.m.cidx = v - 1;
      }
    }
    __syncthreads();                     // also orders prev center's LDS reuse
    const int c = sh.m.qc;
    if (c >= 8*S_PTS) break;
    const int b = c >> 10;
    const int s = c & (S_PTS - 1);
    const int cen = sh.m.cidx;
    const float* pc = xyz + ((size_t)b * N_PTS + cen) * 3;
    const float cx = pc[0], cy = pc[1], cz = pc[2];   // same bits the producer stored

    // --- ball query (wave 0 only), ordered first-32 selection via ballot ---
    if (w == 0){
      const float* xb = xyz + (size_t)b * N_PTS * 3;
      const float R2 = 0.2f * 0.2f;
      int have = 0, first = -1;
      for (int chunk = 0; chunk < 64 && have < K_SAMP; ++chunk){
        int p = chunk * 64 + lane;
        float dx = __fsub_rn(xb[p*3+0], cx);
        float dy = __fsub_rn(xb[p*3+1], cy);
        float dz = __fsub_rn(xb[p*3+2], cz);
        float d2 = __fadd_rn(__fadd_rn(__fmul_rn(dx,dx), __fmul_rn(dy,dy)), __fmul_rn(dz,dz));
        bool hit = d2 < R2;
        unsigned long long mask = __ballot(hit);
        if (mask){
          if (first < 0) first = chunk*64 + (__ffsll(mask) - 1);
          int pre = __popcll(mask & ((1ull << lane) - 1ull));
          if (hit && (have + pre) < K_SAMP) sh.m.sidx[have + pre] = p;
          have += __popcll(mask);
          if (have > K_SAMP) have = K_SAMP;
        }
      }
      if (first < 0) first = 0;
      if (lane < K_SAMP - have) sh.m.sidx[have + lane] = first;
    }
    __syncthreads();

    // --- gather: features -> gT1[p][0..63], relative xyz -> gT1[p][64..66] ---
    {
      int p = t >> 3, q = t & 7;
      int src = sh.m.sidx[p];
      const float* fr = feat + ((size_t)b * N_PTS + src) * 64 + q*8;
      unsigned u[4];
#pragma unroll
      for (int jj = 0; jj < 4; ++jj){
        unsigned lo = (unsigned short)f2b(fr[2*jj]);
        unsigned hi = (unsigned short)f2b(fr[2*jj+1]);
        u[jj] = lo | (hi << 16);
      }
      uint4 v; v.x = u[0]; v.y = u[1]; v.z = u[2]; v.w = u[3];
      *reinterpret_cast<uint4*>(&sh.m.gT1[p*GT1_S + q*8]) = v;
    }
    if (t < 32){
      int src = sh.m.sidx[t];
      const float* pr = xyz + ((size_t)b * N_PTS + src) * 3;
      sh.m.gT1[t*GT1_S + 64] = f2b(__fsub_rn(pr[0], cx));
      sh.m.gT1[t*GT1_S + 65] = f2b(__fsub_rn(pr[1], cy));
      sh.m.gT1[t*GT1_S + 66] = f2b(__fsub_rn(pr[2], cz));
    }
    __syncthreads();

    layer_mfma<64, 3, 96, GT1_S, GT2_S>(w1, sh.m.gT1, sh.m.gT2, sh.m.sbias, w, quad, col);
    __syncthreads();
    layer_mfma<128, 2, 64, GT2_S, GT3_S>(w2, sh.m.gT2, sh.m.gT3, sh.m.sbias + 64, w, quad, col);
    __syncthreads();

    // --- layer 3 + max-pool + DIRECT transposed store to out_feat(b,c,s) ---
    for (int m0 = w*16; m0 < 256; m0 += 64){
      f32x4 acc0 = {0,0,0,0}, acc1 = {0,0,0,0};
#pragma unroll
      for (int kc = 0; kc < 4; ++kc){
        bf16x8 a  = *reinterpret_cast<const bf16x8*>(w3 + (size_t)(m0+col)*128 + kc*32 + quad*8);
        bf16x8 b0 = *reinterpret_cast<const bf16x8*>(sh.m.gT3 + col*GT3_S + kc*32 + quad*8);
        bf16x8 b1 = *reinterpret_cast<const bf16x8*>(sh.m.gT3 + (16+col)*GT3_S + kc*32 + quad*8);
        acc0 = __builtin_amdgcn_mfma_f32_16x16x32_bf16(a, b0, acc0, 0, 0, 0);
        acc1 = __builtin_amdgcn_mfma_f32_16x16x32_bf16(a, b1, acc1, 0, 0, 0);
      }
      float vm[4];
#pragma unroll
      for (int r = 0; r < 4; ++r) vm[r] = fmaxf(acc0[r], acc1[r]);
#pragma unroll
      for (int off = 1; off < 16; off <<= 1){
#pragma unroll
        for (int r = 0; r < 4; ++r) vm[r] = fmaxf(vm[r], __shfl_xor(vm[r], off, 16));
      }
      if (col == 0){
#pragma unroll
        for (int r = 0; r < 4; ++r){
          int ch = m0 + quad*4 + r;
          out_feat[((size_t)b*256 + ch)*S_PTS + s] =
              fmaxf(vm[r] + sh.m.sbias[192 + ch], 0.0f);
        }
      }
    }
    // no tail barrier: next iteration's queue-grab barrier protects LDS reuse
  }
}

extern "C" void kernel_launch(void* const* d_in, const int* in_sizes, int n_in,
                              void* d_out, int out_size, void* d_ws, size_t ws_size,
                              hipStream_t stream){
  const float* xyz  = (const float*)d_in[0];
  const float* feat = (const float*)d_in[1];
  const float* W1   = (const float*)d_in[2];
  const float* b1   = (const float*)d_in[3];
  const float* W2   = (const float*)d_in[4];
  const float* b2   = (const float*)d_in[5];
  const float* W3   = (const float*)d_in[6];
  const float* b3   = (const float*)d_in[7];

  float* out        = (float*)d_out;
  float* out_newxyz = out;                        // 8*1024*3   = 24576
  float* out_feat   = out + 24576;                // 8*256*1024 = 2097152
  float* out_inds   = out + 24576 + 2097152;      // 8*1024     = 8192 (as float)

  char*  ws     = (char*)d_ws;
  short* ws_w   = (short*)ws;                       // 94208 B of bf16 weights
  int*   ready  = (int*)(ws + 94208);               // 8192 x 64B ready slots = 512 KB
  int*   ctrl   = (int*)(ws + 94208 + 524288);      // [0..7] CU tags, [8] queue

  wconv_kernel<<<32, 256, 0, stream>>>(W1, W2, W3, ws_w, ready, ctrl);
  fused_kernel<<<8 + NCONS, 256, 0, stream>>>(xyz, feat, b1, b2, b3, ws_w,
                                              out_newxyz, out_inds, ready, ctrl,
                                              out_feat);
}